// Round 2
// baseline (214.689 us; speedup 1.0000x reference)
//
#include <hip/hip_runtime.h>

// Linear collapse of the whole network (no activation anywhere in the ref):
//   out[b] = x[b,:]·u + C
//   v[g]   = sum_h W2[h]*W1[h,g]
//   u[s]   = sum_{e: snp_idx[e]==s} edge_w[e]*v[gene_idx[e]]
//   C      = gene_bias·v + W2·b1 + b2
//
// Kernel 1: zero u + compute v. 282 blocks x 512 thr (64 genes x 8 h-groups):
//           all 256 CUs engaged (vs 141 before); per-block C-partials.
// Kernel 2: edge scatter into u (atomicAdd, 8 edges/thread) PLUS 256 prefetch
//           blocks that touch the first ~33 MB of x into L3 (Infinity Cache is
//           memory-side, shared): fills the HBM idle time under the
//           atomic-latency-bound scatter so phase-3 rows hit L3.
// Kernel 3: B-row GEMV x·u, nontemporal x stream, dual accumulators,
//           Cpart folded into the reduction seed.

typedef float  fv4 __attribute__((ext_vector_type(4)));
typedef int    iv4 __attribute__((ext_vector_type(4)));

__global__ __launch_bounds__(512)
void compute_v_kernel(const float* __restrict__ W1,
                      const float* __restrict__ W2,
                      const float* __restrict__ b1,
                      const float* __restrict__ b2,
                      const float* __restrict__ gene_bias,
                      float* __restrict__ v,
                      float* __restrict__ Cpart,
                      float4* __restrict__ u4,
                      int G, int H, int nU4)
{
    __shared__ float red[512];
    const int tid = threadIdx.x;

    // Zero-init u (covers any float4 padding too). Independent of v work.
    {
        const int gid = blockIdx.x * 512 + tid;
        const int tot = gridDim.x * 512;
        const float4 z = make_float4(0.f, 0.f, 0.f, 0.f);
        for (int i = gid; i < nU4; i += tot) u4[i] = z;
    }

    const int gl = tid & 63;       // gene lane within 64-wide tile
    const int hg = tid >> 6;       // h-group 0..7 (wave-uniform)
    const int g  = blockIdx.x * 64 + gl;

    float acc = 0.f;
    if (g < G) {
        #pragma unroll 4
        for (int h = hg; h < H; h += 8) {
            // W2 scalar (cached) load; W1 coalesced 64-lane stream, read once.
            acc += W2[h] * __builtin_nontemporal_load(&W1[(size_t)h * G + g]);
        }
    }
    red[tid] = acc;
    __syncthreads();

    float cc = 0.f;
    if (hg == 0 && g < G) {
        float vg = 0.f;
        #pragma unroll
        for (int k = 0; k < 8; ++k) vg += red[gl + 64 * k];  // bank = gl%32: conflict-free
        v[g] = vg;
        cc = gene_bias[g] * vg;
    }
    if (blockIdx.x == 0) {
        for (int h = tid; h < H; h += 512) cc += W2[h] * b1[h];
        if (tid == 0) cc += b2[0];
    }
    __syncthreads();
    red[tid] = cc;
    __syncthreads();
    for (int s = 256; s > 0; s >>= 1) {
        if (tid < s) red[tid] += red[tid + s];
        __syncthreads();
    }
    if (tid == 0) Cpart[blockIdx.x] = red[0];   // every block writes: no init, no atomics
}

__global__ __launch_bounds__(256)
void scatter_u_kernel(const int* __restrict__ snp_idx,
                      const int* __restrict__ gene_idx,
                      const float* __restrict__ edge_w,
                      const float* __restrict__ v,
                      float* __restrict__ u,
                      int E, int nEB,
                      const float* __restrict__ x, long long xTotal)
{
    const int tid = threadIdx.x;
    if ((int)blockIdx.x >= nEB) {
        // ---- x-prefetch block: warm the first ~33 MB of x into L3 while the
        // scatter blocks (atomic-latency-bound) leave HBM BW idle. One regular
        // (allocating) load per 64B line; asm keeps the load live (rule #17).
        const long long pb = blockIdx.x - nEB;
        #pragma unroll
        for (int k = 0; k < 8; ++k) {
            const long long line = pb * 2048 + k * 256 + tid;   // 64B lines
            const long long off  = line * 16;
            if (off < xTotal) {
                float t = x[off];
                asm volatile("" :: "v"(t));
            }
        }
        return;
    }

    const long long i8   = (long long)blockIdx.x * 256 + tid;
    const long long base = i8 * 8;
    if (base + 7 < E) {
        const iv4 s0 = __builtin_nontemporal_load((const iv4*)(snp_idx  + base));
        const iv4 s1 = __builtin_nontemporal_load((const iv4*)(snp_idx  + base + 4));
        const iv4 g0 = __builtin_nontemporal_load((const iv4*)(gene_idx + base));
        const iv4 g1 = __builtin_nontemporal_load((const iv4*)(gene_idx + base + 4));
        const fv4 w0 = __builtin_nontemporal_load((const fv4*)(edge_w   + base));
        const fv4 w1 = __builtin_nontemporal_load((const fv4*)(edge_w   + base + 4));
        // v gathers hit L1/L2 (72 KB, hot); compute all products before atomics (ILP)
        const float p0 = w0.x * v[g0.x];
        const float p1 = w0.y * v[g0.y];
        const float p2 = w0.z * v[g0.z];
        const float p3 = w0.w * v[g0.w];
        const float p4 = w1.x * v[g1.x];
        const float p5 = w1.y * v[g1.y];
        const float p6 = w1.z * v[g1.z];
        const float p7 = w1.w * v[g1.w];
        atomicAdd(&u[s0.x], p0);
        atomicAdd(&u[s0.y], p1);
        atomicAdd(&u[s0.z], p2);
        atomicAdd(&u[s0.w], p3);
        atomicAdd(&u[s1.x], p4);
        atomicAdd(&u[s1.y], p5);
        atomicAdd(&u[s1.z], p6);
        atomicAdd(&u[s1.w], p7);
    } else {
        for (long long i = base; i < E; ++i)
            atomicAdd(&u[snp_idx[i]], edge_w[i] * v[gene_idx[i]]);
    }
}

__global__ __launch_bounds__(1024)
void output_kernel(const float* __restrict__ x,
                   const float* __restrict__ u,
                   const float* __restrict__ Cpart,
                   int nC,
                   float* __restrict__ out,
                   int S)
{
    const int b   = blockIdx.x;
    const int tid = threadIdx.x;
    float acc0 = (tid < nC) ? Cpart[tid] : 0.f;   // fold constant term into reduction
    float acc1 = 0.f;

    const float* xr = x + (size_t)b * S;
    const int S4 = S >> 2;
    const fv4* x4 = (const fv4*)xr;               // b*S*4 is 16B-aligned when S%4==0
    const fv4* u4 = (const fv4*)u;

    int i = tid;
    for (; i + 1024 < S4; i += 2048) {
        // x: streamed once, nontemporal (keep u resident in L2); u: cached
        const fv4 a0 = __builtin_nontemporal_load(&x4[i]);
        const fv4 a1 = __builtin_nontemporal_load(&x4[i + 1024]);
        const fv4 c0 = u4[i];
        const fv4 c1 = u4[i + 1024];
        acc0 += a0.x * c0.x + a0.y * c0.y + a0.z * c0.z + a0.w * c0.w;
        acc1 += a1.x * c1.x + a1.y * c1.y + a1.z * c1.z + a1.w * c1.w;
    }
    for (; i < S4; i += 1024) {
        const fv4 a = __builtin_nontemporal_load(&x4[i]);
        const fv4 c = u4[i];
        acc0 += a.x * c.x + a.y * c.y + a.z * c.z + a.w * c.w;
    }
    for (int j = (S4 << 2) + tid; j < S; j += 1024) acc0 += xr[j] * u[j];
    acc0 += acc1;

    for (int off = 32; off > 0; off >>= 1) acc0 += __shfl_down(acc0, off, 64);
    __shared__ float wsum[16];
    const int wave = tid >> 6;
    const int lane = tid & 63;
    if (lane == 0) wsum[wave] = acc0;
    __syncthreads();
    if (tid == 0) {
        float t = 0.f;
        for (int w = 0; w < 16; ++w) t += wsum[w];
        out[b] = t;
    }
}

extern "C" void kernel_launch(void* const* d_in, const int* in_sizes, int n_in,
                              void* d_out, int out_size, void* d_ws, size_t ws_size,
                              hipStream_t stream)
{
    const float* x         = (const float*)d_in[0];
    const int*   snp_idx   = (const int*)  d_in[1];
    const int*   gene_idx  = (const int*)  d_in[2];
    const float* edge_w    = (const float*)d_in[3];
    const float* gene_bias = (const float*)d_in[4];
    const float* W1        = (const float*)d_in[5];
    const float* b1        = (const float*)d_in[6];
    const float* W2        = (const float*)d_in[7];
    const float* b2        = (const float*)d_in[8];
    float* out = (float*)d_out;

    const int B = out_size;            // 256
    const int E = in_sizes[1];         // 600000
    const int G = in_sizes[4];         // 18000
    const int H = in_sizes[6];         // 256
    const int S = in_sizes[0] / B;     // 100000

    // Workspace layout: u[nU4*4] | v[G] | Cpart[nbv]
    const int nU4 = (S + 3) / 4;
    float* u     = (float*)d_ws;
    float* v     = u + (size_t)nU4 * 4;
    const int nbv = (G + 63) / 64;     // 282 (must stay <= 1024 for Cpart fold)
    float* Cpart = v + G;

    compute_v_kernel<<<nbv, 512, 0, stream>>>(W1, W2, b1, b2, gene_bias,
                                              v, Cpart, (float4*)u, G, H, nU4);

    const int nE8 = (E + 7) / 8;
    const int nEB = (nE8 + 255) / 256;        // 293 edge-scatter blocks
    const int nPB = 256;                      // 256 x-prefetch blocks (~33 MB)
    scatter_u_kernel<<<nEB + nPB, 256, 0, stream>>>(snp_idx, gene_idx, edge_w,
                                                    v, u, E, nEB,
                                                    x, (long long)B * S);

    output_kernel<<<B, 1024, 0, stream>>>(x, u, Cpart, nbv, out, S);
}

// Round 3
// 208.102 us; speedup vs baseline: 1.0317x; 1.0317x over previous
//
#include <hip/hip_runtime.h>

// Linear collapse of the whole network (no activation anywhere in the ref):
//   out[b] = x[b,:]·u + C
//   v[g]   = sum_h W2[h]*W1[h,g]
//   u[s]   = sum_{e: snp_idx[e]==s} edge_w[e]*v[gene_idx[e]]
//   C      = gene_bias·v + W2·b1 + b2
//
// Round-3 note: round-2's L3-prefetch-during-scatter REGRESSED (209.3 -> 214.7):
// the 33 MB warm-up extended the scatter kernel's critical path by ~5 us,
// exactly eating the predicted phase-3 gain. Reverted to the round-1 best.
//
// Kernel 1: zero u (grid-stride float4), compute v (141 blocks x 1024 thr:
//           128 genes/block, 8 h-groups -> single block round, 32-iter chains),
//           write per-block C-partials (race-free, no init needed).
// Kernel 2: edge scatter into u (atomicAdd, 8 edges/thread, nontemporal loads).
// Kernel 3: B-row GEMV x·u, nontemporal x stream (keeps u L2-resident),
//           2-way unrolled dual accumulators; Cpart folded into reduction.

typedef float  fv4 __attribute__((ext_vector_type(4)));
typedef int    iv4 __attribute__((ext_vector_type(4)));

__global__ __launch_bounds__(1024)
void compute_v_kernel(const float* __restrict__ W1,
                      const float* __restrict__ W2,
                      const float* __restrict__ b1,
                      const float* __restrict__ b2,
                      const float* __restrict__ gene_bias,
                      float* __restrict__ v,
                      float* __restrict__ Cpart,
                      float4* __restrict__ u4,
                      int G, int H, int nU4)
{
    __shared__ float red[1024];
    const int tid = threadIdx.x;

    // Zero-init u (covers any float4 padding too). Independent of v work.
    {
        const int gid = blockIdx.x * 1024 + tid;
        const int tot = gridDim.x * 1024;
        const float4 z = make_float4(0.f, 0.f, 0.f, 0.f);
        for (int i = gid; i < nU4; i += tot) u4[i] = z;
    }

    const int gl = tid & 127;      // gene lane within 128-wide tile
    const int hg = tid >> 7;       // h-group 0..7 (wave-uniform)
    const int g  = blockIdx.x * 128 + gl;

    float acc = 0.f;
    if (g < G) {
        #pragma unroll 4
        for (int h = hg; h < H; h += 8) {
            // W2 scalar (cached) load; W1 coalesced 64-lane stream, read once.
            acc += W2[h] * __builtin_nontemporal_load(&W1[(size_t)h * G + g]);
        }
    }
    red[tid] = acc;
    __syncthreads();

    float cc = 0.f;
    if (hg == 0 && g < G) {
        float vg = 0.f;
        #pragma unroll
        for (int k = 0; k < 8; ++k) vg += red[gl + 128 * k];  // lane%32 banks: conflict-free
        v[g] = vg;
        cc = gene_bias[g] * vg;
    }
    if (blockIdx.x == 0) {
        for (int h = tid; h < H; h += 1024) cc += W2[h] * b1[h];
        if (tid == 0) cc += b2[0];
    }
    __syncthreads();
    red[tid] = cc;
    __syncthreads();
    for (int s = 512; s > 0; s >>= 1) {
        if (tid < s) red[tid] += red[tid + s];
        __syncthreads();
    }
    if (tid == 0) Cpart[blockIdx.x] = red[0];   // every block writes: no init, no atomics
}

__global__ __launch_bounds__(256)
void scatter_u_kernel(const int* __restrict__ snp_idx,
                      const int* __restrict__ gene_idx,
                      const float* __restrict__ edge_w,
                      const float* __restrict__ v,
                      float* __restrict__ u,
                      int E)
{
    const long long i8   = (long long)blockIdx.x * 256 + threadIdx.x;
    const long long base = i8 * 8;
    if (base + 7 < E) {
        const iv4 s0 = __builtin_nontemporal_load((const iv4*)(snp_idx  + base));
        const iv4 s1 = __builtin_nontemporal_load((const iv4*)(snp_idx  + base + 4));
        const iv4 g0 = __builtin_nontemporal_load((const iv4*)(gene_idx + base));
        const iv4 g1 = __builtin_nontemporal_load((const iv4*)(gene_idx + base + 4));
        const fv4 w0 = __builtin_nontemporal_load((const fv4*)(edge_w   + base));
        const fv4 w1 = __builtin_nontemporal_load((const fv4*)(edge_w   + base + 4));
        // v gathers hit L1/L2 (72 KB, hot); compute all products before atomics (ILP)
        const float p0 = w0.x * v[g0.x];
        const float p1 = w0.y * v[g0.y];
        const float p2 = w0.z * v[g0.z];
        const float p3 = w0.w * v[g0.w];
        const float p4 = w1.x * v[g1.x];
        const float p5 = w1.y * v[g1.y];
        const float p6 = w1.z * v[g1.z];
        const float p7 = w1.w * v[g1.w];
        atomicAdd(&u[s0.x], p0);
        atomicAdd(&u[s0.y], p1);
        atomicAdd(&u[s0.z], p2);
        atomicAdd(&u[s0.w], p3);
        atomicAdd(&u[s1.x], p4);
        atomicAdd(&u[s1.y], p5);
        atomicAdd(&u[s1.z], p6);
        atomicAdd(&u[s1.w], p7);
    } else {
        for (long long i = base; i < E; ++i)
            atomicAdd(&u[snp_idx[i]], edge_w[i] * v[gene_idx[i]]);
    }
}

__global__ __launch_bounds__(1024)
void output_kernel(const float* __restrict__ x,
                   const float* __restrict__ u,
                   const float* __restrict__ Cpart,
                   int nC,
                   float* __restrict__ out,
                   int S)
{
    const int b   = blockIdx.x;
    const int tid = threadIdx.x;
    float acc0 = (tid < nC) ? Cpart[tid] : 0.f;   // fold constant term into reduction
    float acc1 = 0.f;

    const float* xr = x + (size_t)b * S;
    const int S4 = S >> 2;
    const fv4* x4 = (const fv4*)xr;               // b*S*4 is 16B-aligned when S%4==0
    const fv4* u4 = (const fv4*)u;

    int i = tid;
    for (; i + 1024 < S4; i += 2048) {
        // x: streamed once, nontemporal (keep u resident in L2); u: cached
        const fv4 a0 = __builtin_nontemporal_load(&x4[i]);
        const fv4 a1 = __builtin_nontemporal_load(&x4[i + 1024]);
        const fv4 c0 = u4[i];
        const fv4 c1 = u4[i + 1024];
        acc0 += a0.x * c0.x + a0.y * c0.y + a0.z * c0.z + a0.w * c0.w;
        acc1 += a1.x * c1.x + a1.y * c1.y + a1.z * c1.z + a1.w * c1.w;
    }
    for (; i < S4; i += 1024) {
        const fv4 a = __builtin_nontemporal_load(&x4[i]);
        const fv4 c = u4[i];
        acc0 += a.x * c.x + a.y * c.y + a.z * c.z + a.w * c.w;
    }
    for (int j = (S4 << 2) + tid; j < S; j += 1024) acc0 += xr[j] * u[j];
    acc0 += acc1;

    for (int off = 32; off > 0; off >>= 1) acc0 += __shfl_down(acc0, off, 64);
    __shared__ float wsum[16];
    const int wave = tid >> 6;
    const int lane = tid & 63;
    if (lane == 0) wsum[wave] = acc0;
    __syncthreads();
    if (tid == 0) {
        float t = 0.f;
        for (int w = 0; w < 16; ++w) t += wsum[w];
        out[b] = t;
    }
}

extern "C" void kernel_launch(void* const* d_in, const int* in_sizes, int n_in,
                              void* d_out, int out_size, void* d_ws, size_t ws_size,
                              hipStream_t stream)
{
    const float* x         = (const float*)d_in[0];
    const int*   snp_idx   = (const int*)  d_in[1];
    const int*   gene_idx  = (const int*)  d_in[2];
    const float* edge_w    = (const float*)d_in[3];
    const float* gene_bias = (const float*)d_in[4];
    const float* W1        = (const float*)d_in[5];
    const float* b1        = (const float*)d_in[6];
    const float* W2        = (const float*)d_in[7];
    const float* b2        = (const float*)d_in[8];
    float* out = (float*)d_out;

    const int B = out_size;            // 256
    const int E = in_sizes[1];         // 600000
    const int G = in_sizes[4];         // 18000
    const int H = in_sizes[6];         // 256
    const int S = in_sizes[0] / B;     // 100000

    // Workspace layout: u[nU4*4] | v[G] | Cpart[nbv]
    const int nU4 = (S + 3) / 4;
    float* u     = (float*)d_ws;
    float* v     = u + (size_t)nU4 * 4;
    const int nbv = (G + 127) / 128;   // 141: single block-round on 256 CUs (no tail)
    float* Cpart = v + G;

    compute_v_kernel<<<nbv, 1024, 0, stream>>>(W1, W2, b1, b2, gene_bias,
                                               v, Cpart, (float4*)u, G, H, nU4);

    const int nE8 = (E + 7) / 8;
    scatter_u_kernel<<<(nE8 + 255) / 256, 256, 0, stream>>>(snp_idx, gene_idx, edge_w,
                                                            v, u, E);

    output_kernel<<<B, 1024, 0, stream>>>(x, u, Cpart, nbv, out, S);
}